// Round 1
// 408.877 us; speedup vs baseline: 1.0129x; 1.0129x over previous
//
#include <hip/hip_runtime.h>
#include <hip/hip_bf16.h>
#include <math.h>

#define N_NODES 100000
#define DIM 128
#define NH 8
#define NC 16
#define E_EDGES 400000
#define LN_EPS 1e-3f
#define SCAN_B 1024

typedef __attribute__((ext_vector_type(8))) short short8v;
typedef __attribute__((ext_vector_type(4))) short short4v;
typedef __attribute__((ext_vector_type(4))) float float4v;

__device__ __forceinline__ short bf16bits(float v) {
    __hip_bfloat16 b = __float2bfloat16(v);
    return *(short*)&b;
}

// ---------------- fused transposed weights (bf16) + fused biases -------------
// Wt[c][d], c in [0,768): sections of 128 cols:
//  0: Wk·BD(Watt0)·prior0/sqrt(C)   1: Wk·BD(Watt1)·prior1/sqrt(C)
//  2: Wm·BD(Wmsg0)                  3: Wm·BD(Wmsg1)
//  4: Wq                            5: Wa
__global__ __launch_bounds__(128) void fuse_weights(
    const float* __restrict__ Wk, const float* __restrict__ bk,
    const float* __restrict__ Wm, const float* __restrict__ bm,
    const float* __restrict__ Wq, const float* __restrict__ bq,
    const float* __restrict__ Wa, const float* __restrict__ ba,
    const float* __restrict__ Watt0, const float* __restrict__ Wmsg0,
    const float* __restrict__ Watt1, const float* __restrict__ Wmsg1,
    const float* __restrict__ prior0, const float* __restrict__ prior1,
    __hip_bfloat16* __restrict__ Wt, float* __restrict__ bias)
{
    const int c = blockIdx.x;        // 0..767
    const int d = threadIdx.x;       // 0..127
    const int sec = c >> 7, j = c & 127, h = j >> 4, l = j & 15;
    float v, b;
    if (sec == 4)      { v = Wq[d * DIM + j]; b = bq[j]; }
    else if (sec == 5) { v = Wa[d * DIM + j]; b = ba[j]; }
    else {
        const float* W1 = (sec < 2) ? Wk : Wm;
        const float* bs = (sec < 2) ? bk : bm;
        const float* W2 = (sec == 0) ? Watt0 : (sec == 1) ? Watt1
                          : (sec == 2) ? Wmsg0 : Wmsg1;
        float scale = (sec == 0) ? prior0[h] * 0.25f
                    : (sec == 1) ? prior1[h] * 0.25f : 1.f;
        float s = 0.f, sb = 0.f;
        #pragma unroll
        for (int kk = 0; kk < NC; ++kk) {
            float w2 = W2[h * 256 + kk * 16 + l];
            s  = fmaf(W1[d * DIM + h * 16 + kk], w2, s);
            sb = fmaf(bs[h * 16 + kk], w2, sb);
        }
        v = s * scale; b = sb * scale;
    }
    Wt[(size_t)c * DIM + d] = __float2bfloat16(v);
    if (d == 0) bias[c] = b;
}

// ---------------- proj: bf16 MFMA GEMM [N,128]@[128,640] ---------------------
// Swapped-operand formulation: D = W·x^T per tile, so each lane's C/D fragment
// is 4 CONSECUTIVE output columns of ONE node -> direct 8B global stores, no
// output LDS staging, ONE barrier total (after cooperative x staging).
// x tile staged once in LDS (bf16, XOR-swizzled 16B chunks => conflict-free
// ds_write_b128 and ds_read_b128 on both sides).
__global__ __launch_bounds__(256) void proj_mfma(
    const float* __restrict__ x,             // [N][128] fp32
    const __hip_bfloat16* __restrict__ Wt,   // [768][128]
    const float* __restrict__ bias,          // [768]
    __hip_bfloat16* __restrict__ kattC,      // [2N][128]
    __hip_bfloat16* __restrict__ mmsgC,      // [2N][128]
    __hip_bfloat16* __restrict__ qb)         // [N][128]
{
    __shared__ __align__(16) short xs[32 * DIM];   // 8 KB
    const int tid = threadIdx.x;
    const int wave = tid >> 6, lane = tid & 63;
    const int quad = lane >> 4, mcol = lane & 15;
    const int r0 = blockIdx.x * 32;

    // ---- cooperative stage: 32x128 f32 -> bf16 in LDS (16 elems/thread) ----
    {
        const int row = tid >> 3, c8 = tid & 7;          // row 0..31, 16-col grp
        const float* xp = x + (size_t)(r0 + row) * DIM + c8 * 16;
        float4v f[4];
        #pragma unroll
        for (int i = 0; i < 4; ++i) f[i] = *(const float4v*)(xp + i * 4);
        short8v s0, s1;
        #pragma unroll
        for (int j = 0; j < 8; ++j) {
            s0[j] = bf16bits(((const float*)f)[j]);
            s1[j] = bf16bits(((const float*)f)[j + 8]);
        }
        short* base = xs + row * DIM;
        *(short8v*)(base + (((2 * c8)     ^ (row & 7)) * 8)) = s0;
        *(short8v*)(base + (((2 * c8 + 1) ^ (row & 7)) * 8)) = s1;
    }
    __syncthreads();

    // ---- B fragments (x^T): col=lane&15 -> node, k = quad*8 + j ------------
    short8v b0[4], b1[4];
    #pragma unroll
    for (int kb = 0; kb < 4; ++kb) {
        const int ch = quad + kb * 4;                    // 16B chunk 0..15
        b0[kb] = *(const short8v*)(xs + mcol * DIM + ((ch ^ (mcol & 7)) * 8));
        b1[kb] = *(const short8v*)(xs + (mcol + 16) * DIM + ((ch ^ (mcol & 7)) * 8));
    }

    // ---- 5 sections x 2 col-tiles per wave; direct stores ------------------
    #pragma unroll
    for (int s = 0; s < 5; ++s) {
        __hip_bfloat16* dst =
            (s == 0) ? kattC :
            (s == 1) ? kattC + (size_t)N_NODES * DIM :
            (s == 2) ? mmsgC :
            (s == 3) ? mmsgC + (size_t)N_NODES * DIM :
                       qb;
        short* drow0 = (short*)dst + (size_t)(r0 + mcol) * DIM;
        short* drow1 = drow0 + 16 * DIM;
        #pragma unroll
        for (int tp = 0; tp < 2; ++tp) {
            const int ct = (wave * 2 + tp) * 16;         // wave owns 32 contig cols
            const int c0 = s * 128 + ct;
            // A fragments (W): row=lane&15 -> out col c0+mcol, k = quad*8 + j
            const short* wp = (const short*)Wt + (size_t)(c0 + mcol) * DIM + quad * 8;
            float4v acc0 = {0.f, 0.f, 0.f, 0.f};
            float4v acc1 = {0.f, 0.f, 0.f, 0.f};
            #pragma unroll
            for (int kb = 0; kb < 4; ++kb) {
                short8v af = *(const short8v*)(wp + kb * 32);
                acc0 = __builtin_amdgcn_mfma_f32_16x16x32_bf16(af, b0[kb], acc0, 0, 0, 0);
                acc1 = __builtin_amdgcn_mfma_f32_16x16x32_bf16(af, b1[kb], acc1, 0, 0, 0);
            }
            // D: col=lane&15 -> node (mcol group), row=quad*4+g -> out col
            const float4v b4 = *(const float4v*)(bias + c0 + quad * 4);
            short4v o0, o1;
            #pragma unroll
            for (int g = 0; g < 4; ++g) {
                o0[g] = bf16bits(acc0[g] + b4[g]);
                o1[g] = bf16bits(acc1[g] + b4[g]);
            }
            *(short4v*)(drow0 + ct + quad * 4) = o0;
            *(short4v*)(drow1 + ct + quad * 4) = o1;
        }
    }
}

// ---------------- CSR build ----------------
__global__ __launch_bounds__(256) void hist_kernel(
    const int* __restrict__ dst0, const int* __restrict__ dst1,
    int* __restrict__ counts)
{
    int e = blockIdx.x * 256 + threadIdx.x;
    if (e < E_EDGES) atomicAdd(&counts[dst0[e]], 1);
    int e1 = e - E_EDGES;
    if (e1 >= 0 && e1 < E_EDGES) atomicAdd(&counts[dst1[e1]], 1);
}

__global__ __launch_bounds__(SCAN_B) void scanA_kernel(
    const int* __restrict__ counts, int* __restrict__ row_ptr,
    int* __restrict__ bsum)
{
    __shared__ int buf[2][SCAN_B];
    int i = blockIdx.x * SCAN_B + threadIdx.x;
    int v = (i < N_NODES) ? counts[i] : 0;
    int cur = 0;
    buf[0][threadIdx.x] = v;
    __syncthreads();
    #pragma unroll
    for (int off = 1; off < SCAN_B; off <<= 1) {
        int t = buf[cur][threadIdx.x];
        int add = (threadIdx.x >= off) ? buf[cur][threadIdx.x - off] : 0;
        buf[cur ^ 1][threadIdx.x] = t + add;
        cur ^= 1;
        __syncthreads();
    }
    int inc = buf[cur][threadIdx.x];
    if (i < N_NODES) row_ptr[i] = inc - v;
    if (threadIdx.x == SCAN_B - 1) bsum[blockIdx.x] = inc;
}

// parallel exclusive scan of the (<=128) block sums, single block
__global__ __launch_bounds__(128) void scanB_kernel(int* __restrict__ bsum, int nblocks)
{
    __shared__ int buf[2][128];
    int t = threadIdx.x;
    int v = (t < nblocks) ? bsum[t] : 0;
    buf[0][t] = v;
    __syncthreads();
    int cur = 0;
    #pragma unroll
    for (int off = 1; off < 128; off <<= 1) {
        int a = buf[cur][t];
        if (t >= off) a += buf[cur][t - off];
        buf[cur ^ 1][t] = a;
        cur ^= 1;
        __syncthreads();
    }
    if (t < nblocks) bsum[t] = buf[cur][t] - v;   // exclusive
}

__global__ __launch_bounds__(SCAN_B) void scanC_kernel(
    int* __restrict__ row_ptr, int* __restrict__ cursor,
    const int* __restrict__ bsum)
{
    int i = blockIdx.x * SCAN_B + threadIdx.x;
    if (i < N_NODES) {
        int r = row_ptr[i] + bsum[blockIdx.x];
        row_ptr[i] = r;
        cursor[i] = r;
    }
}

__global__ __launch_bounds__(256) void scatter_kernel(
    const int* __restrict__ src0, const int* __restrict__ dst0,
    const int* __restrict__ src1, const int* __restrict__ dst1,
    int* __restrict__ cursor, unsigned int* __restrict__ eidx)
{
    int e = blockIdx.x * 256 + threadIdx.x;
    if (e < E_EDGES) {
        int d = dst0[e];
        int pos = atomicAdd(&cursor[d], 1);
        eidx[pos] = (unsigned int)src0[e];
    }
    int e1 = e - E_EDGES;
    if (e1 >= 0 && e1 < E_EDGES) {
        int d = dst1[e1];
        int pos = atomicAdd(&cursor[d], 1);
        eidx[pos] = (unsigned int)(src1[e1] + N_NODES);
    }
}

// ---------------- aggregation: one wave per node, no atomics -----------------
// Lane owns channel pair (2*lane, 2*lane+1). Writes gelu(pooled/denom) in bf16.
__global__ __launch_bounds__(256) void agg_kernel(
    const __hip_bfloat162* __restrict__ katt,   // [2N][64] channel pairs
    const __hip_bfloat162* __restrict__ mmsg,   // [2N][64]
    const __hip_bfloat162* __restrict__ qb2,    // [N][64]
    const int* __restrict__ row_ptr, const int* __restrict__ counts,
    const unsigned int* __restrict__ eidx,
    __hip_bfloat162* __restrict__ pooled2)      // [N][64]
{
    const int wave = threadIdx.x >> 6, lane = threadIdx.x & 63;
    const int n = blockIdx.x * 4 + wave;
    if (n >= N_NODES) return;
    const int start = row_ptr[n], cnt = counts[n];
    __hip_bfloat162 qv = qb2[(size_t)n * 64 + lane];
    const float qx = __bfloat162float(qv.x), qy = __bfloat162float(qv.y);

    float accx = 0.f, accy = 0.f, den = 0.f;
    int i = 0;
    for (; i + 2 <= cnt; i += 2) {
        unsigned int r0 = eidx[start + i];
        unsigned int r1 = eidx[start + i + 1];
        __hip_bfloat162 ka0 = katt[(size_t)r0 * 64 + lane];
        __hip_bfloat162 ka1 = katt[(size_t)r1 * 64 + lane];
        __hip_bfloat162 mg0 = mmsg[(size_t)r0 * 64 + lane];
        __hip_bfloat162 mg1 = mmsg[(size_t)r1 * 64 + lane];
        float p0 = fmaf(__bfloat162float(ka0.x), qx,
                        __bfloat162float(ka0.y) * qy);
        float p1 = fmaf(__bfloat162float(ka1.x), qx,
                        __bfloat162float(ka1.y) * qy);
        p0 += __shfl_xor(p0, 1, 64); p0 += __shfl_xor(p0, 2, 64); p0 += __shfl_xor(p0, 4, 64);
        p1 += __shfl_xor(p1, 1, 64); p1 += __shfl_xor(p1, 2, 64); p1 += __shfl_xor(p1, 4, 64);
        float e0 = __expf(p0), e1 = __expf(p1);
        accx = fmaf(e0, __bfloat162float(mg0.x), accx);
        accy = fmaf(e0, __bfloat162float(mg0.y), accy);
        accx = fmaf(e1, __bfloat162float(mg1.x), accx);
        accy = fmaf(e1, __bfloat162float(mg1.y), accy);
        den += e0 + e1;
    }
    if (i < cnt) {
        unsigned int r0 = eidx[start + i];
        __hip_bfloat162 ka0 = katt[(size_t)r0 * 64 + lane];
        __hip_bfloat162 mg0 = mmsg[(size_t)r0 * 64 + lane];
        float p0 = fmaf(__bfloat162float(ka0.x), qx,
                        __bfloat162float(ka0.y) * qy);
        p0 += __shfl_xor(p0, 1, 64); p0 += __shfl_xor(p0, 2, 64); p0 += __shfl_xor(p0, 4, 64);
        float e0 = __expf(p0);
        accx = fmaf(e0, __bfloat162float(mg0.x), accx);
        accy = fmaf(e0, __bfloat162float(mg0.y), accy);
        den += e0;
    }

    float vx = 0.f, vy = 0.f;
    if (den > 0.f) { vx = accx / den; vy = accy / den; }
    vx = 0.5f * vx * (1.f + erff(vx * 0.70710678118654752f));
    vy = 0.5f * vy * (1.f + erff(vy * 0.70710678118654752f));
    __hip_bfloat162 o; o.x = __float2bfloat16(vx); o.y = __float2bfloat16(vy);
    pooled2[(size_t)n * 64 + lane] = o;
}

// ---------------- final: MFMA GEMM(Wa) -> skip -> LayerNorm ------------------
__global__ __launch_bounds__(256) void final_mfma(
    const __hip_bfloat16* __restrict__ pooled,  // [N][128] bf16, gelu applied
    const __hip_bfloat16* __restrict__ Wt,      // [768][128]; rows 640.. = Wa^T
    const float* __restrict__ bias,             // [768]; 640.. = ba
    const float* __restrict__ x,
    const float* __restrict__ skip, const float* __restrict__ gamma,
    const float* __restrict__ beta, float* __restrict__ out)
{
    __shared__ float hs[32][DIM];
    const int wave = threadIdx.x >> 6, lane = threadIdx.x & 63;
    const int quad = lane >> 4, mcol = lane & 15;
    const int r0 = blockIdx.x * 32;

    short8v a0[4], a1[4];
    const short* pp0 = (const short*)pooled + (size_t)(r0 + mcol) * DIM + quad * 8;
    const short* pp1 = pp0 + 16 * DIM;
    #pragma unroll
    for (int kb = 0; kb < 4; ++kb) {
        a0[kb] = *(const short8v*)(pp0 + kb * 32);
        a1[kb] = *(const short8v*)(pp1 + kb * 32);
    }
    const float alpha = 1.f / (1.f + expf(-skip[0]));

    #pragma unroll
    for (int t = 0; t < 2; ++t) {
        const int c0 = wave * 32 + t * 16;
        const short* wp = (const short*)Wt + (size_t)(640 + c0 + mcol) * DIM + quad * 8;
        float4v acc0 = {0.f, 0.f, 0.f, 0.f};
        float4v acc1 = {0.f, 0.f, 0.f, 0.f};
        #pragma unroll
        for (int kb = 0; kb < 4; ++kb) {
            short8v bfr = *(const short8v*)(wp + kb * 32);
            acc0 = __builtin_amdgcn_mfma_f32_16x16x32_bf16(a0[kb], bfr, acc0, 0, 0, 0);
            acc1 = __builtin_amdgcn_mfma_f32_16x16x32_bf16(a1[kb], bfr, acc1, 0, 0, 0);
        }
        const float bcol = bias[640 + c0 + mcol];
        const int cc = c0 + mcol;
        const int rq = quad * 4;
        #pragma unroll
        for (int g = 0; g < 4; ++g) {
            int rA = rq + g, rB = rq + 16 + g;
            hs[rA][cc] = alpha * (acc0[g] + bcol)
                       + (1.f - alpha) * x[(size_t)(r0 + rA) * DIM + cc];
            hs[rB][cc] = alpha * (acc1[g] + bcol)
                       + (1.f - alpha) * x[(size_t)(r0 + rB) * DIM + cc];
        }
    }
    __syncthreads();

    float gam0 = gamma[lane], gam1 = gamma[lane + 64];
    float bet0 = beta[lane],  bet1 = beta[lane + 64];
    for (int r = wave; r < 32; r += 4) {
        int row = r0 + r;
        float v0 = hs[r][lane], v1 = hs[r][lane + 64];
        float s = v0 + v1, s2 = v0 * v0 + v1 * v1;
        #pragma unroll
        for (int off = 1; off < 64; off <<= 1) {
            s  += __shfl_xor(s,  off, 64);
            s2 += __shfl_xor(s2, off, 64);
        }
        float mu = s * (1.f / 128.f);
        float var = s2 * (1.f / 128.f) - mu * mu;
        float rstd = rsqrtf(var + LN_EPS);
        out[(size_t)row * DIM + lane]      = (v0 - mu) * rstd * gam0 + bet0;
        out[(size_t)row * DIM + lane + 64] = (v1 - mu) * rstd * gam1 + bet1;
    }
}

extern "C" void kernel_launch(void* const* d_in, const int* in_sizes, int n_in,
                              void* d_out, int out_size, void* d_ws, size_t ws_size,
                              hipStream_t stream) {
    const float* x     = (const float*)d_in[0];
    const int*   src0  = (const int*)d_in[1];
    const int*   dst0  = (const int*)d_in[2];
    const int*   src1  = (const int*)d_in[3];
    const int*   dst1  = (const int*)d_in[4];
    const float* Wk    = (const float*)d_in[5];
    const float* bk    = (const float*)d_in[6];
    const float* Wm    = (const float*)d_in[7];
    const float* bm    = (const float*)d_in[8];
    const float* Wq    = (const float*)d_in[9];
    const float* bq    = (const float*)d_in[10];
    const float* Wa    = (const float*)d_in[11];
    const float* ba    = (const float*)d_in[12];
    const float* Watt0 = (const float*)d_in[13];
    const float* Wmsg0 = (const float*)d_in[14];
    const float* Watt1 = (const float*)d_in[15];
    const float* Wmsg1 = (const float*)d_in[16];
    const float* prior0= (const float*)d_in[17];
    const float* prior1= (const float*)d_in[18];
    const float* skip  = (const float*)d_in[19];
    const float* gamma = (const float*)d_in[20];
    const float* beta  = (const float*)d_in[21];
    float* out = (float*)d_out;

    const size_t nd = (size_t)N_NODES * DIM;
    // Workspace (~158 MB):
    //   Wt [768*128 bf16] | bias [768 f32] | kattC [2nd bf16] | mmsgC [2nd bf16]
    //   | qb [nd bf16] | pooled [nd bf16] | counts/row_ptr/cursor [N i32]
    //   | bsum [128 i32] | eidx [2E u32]
    char* wsb = (char*)d_ws;
    __hip_bfloat16* Wt    = (__hip_bfloat16*)wsb;  wsb += (size_t)768 * DIM * 2;
    float* bias           = (float*)wsb;           wsb += 768 * 4;
    __hip_bfloat16* kattC = (__hip_bfloat16*)wsb;  wsb += 2 * nd * 2;
    __hip_bfloat16* mmsgC = (__hip_bfloat16*)wsb;  wsb += 2 * nd * 2;
    __hip_bfloat16* qb    = (__hip_bfloat16*)wsb;  wsb += nd * 2;
    __hip_bfloat16* pooled= (__hip_bfloat16*)wsb;  wsb += nd * 2;
    int* counts  = (int*)wsb;                      wsb += (size_t)N_NODES * 4;
    int* row_ptr = (int*)wsb;                      wsb += (size_t)N_NODES * 4;
    int* cursor  = (int*)wsb;                      wsb += (size_t)N_NODES * 4;
    int* bsum    = (int*)wsb;                      wsb += 128 * 4;
    unsigned int* eidx = (unsigned int*)wsb;

    hipMemsetAsync(counts, 0, (size_t)N_NODES * 4, stream);

    const int scan_blocks = (N_NODES + SCAN_B - 1) / SCAN_B;   // 98
    const int edge_blocks = (2 * E_EDGES + 255) / 256;         // 3125

    // CSR chain (independent of projections)
    hist_kernel<<<dim3(edge_blocks), dim3(256), 0, stream>>>(dst0, dst1, counts);
    scanA_kernel<<<dim3(scan_blocks), dim3(SCAN_B), 0, stream>>>(counts, row_ptr, bsum);
    scanB_kernel<<<dim3(1), dim3(128), 0, stream>>>(bsum, scan_blocks);
    scanC_kernel<<<dim3(scan_blocks), dim3(SCAN_B), 0, stream>>>(row_ptr, cursor, bsum);
    scatter_kernel<<<dim3(edge_blocks), dim3(256), 0, stream>>>(
        src0, dst0, src1, dst1, cursor, eidx);

    // Projections
    fuse_weights<<<dim3(768), dim3(128), 0, stream>>>(
        Wk, bk, Wm, bm, Wq, bq, Wa, ba,
        Watt0, Wmsg0, Watt1, Wmsg1, prior0, prior1, Wt, bias);
    proj_mfma<<<dim3(N_NODES / 32), dim3(256), 0, stream>>>(
        x, Wt, bias, kattC, mmsgC, qb);

    agg_kernel<<<dim3((N_NODES + 3) / 4), dim3(256), 0, stream>>>(
        (const __hip_bfloat162*)kattC, (const __hip_bfloat162*)mmsgC,
        (const __hip_bfloat162*)qb, row_ptr, counts, eidx,
        (__hip_bfloat162*)pooled);

    final_mfma<<<dim3(N_NODES / 32), dim3(256), 0, stream>>>(
        pooled, Wt, bias, x, skip, gamma, beta, out);
}

// Round 3
// 372.864 us; speedup vs baseline: 1.1108x; 1.0966x over previous
//
#include <hip/hip_runtime.h>
#include <hip/hip_bf16.h>
#include <math.h>

#define N_NODES 100000
#define DIM 128
#define NH 8
#define NC 16
#define E_EDGES 400000
#define LN_EPS 1e-3f
#define SCAN_B 1024
#define PROJ_GRID 512

typedef __attribute__((ext_vector_type(8))) short short8v;
typedef __attribute__((ext_vector_type(4))) short short4v;
typedef __attribute__((ext_vector_type(4))) float float4v;

__device__ __forceinline__ short bf16bits(float v) {
    __hip_bfloat16 b = __float2bfloat16(v);
    return *(short*)&b;
}

// ---------------- fused transposed weights (bf16) + fused biases -------------
// Wt[c][d], c in [0,768): sections of 128 cols:
//  0: Wk·BD(Watt0)·prior0/sqrt(C)   1: Wk·BD(Watt1)·prior1/sqrt(C)
//  2: Wm·BD(Wmsg0)                  3: Wm·BD(Wmsg1)
//  4: Wq                            5: Wa
__global__ __launch_bounds__(128) void fuse_weights(
    const float* __restrict__ Wk, const float* __restrict__ bk,
    const float* __restrict__ Wm, const float* __restrict__ bm,
    const float* __restrict__ Wq, const float* __restrict__ bq,
    const float* __restrict__ Wa, const float* __restrict__ ba,
    const float* __restrict__ Watt0, const float* __restrict__ Wmsg0,
    const float* __restrict__ Watt1, const float* __restrict__ Wmsg1,
    const float* __restrict__ prior0, const float* __restrict__ prior1,
    __hip_bfloat16* __restrict__ Wt, float* __restrict__ bias)
{
    const int c = blockIdx.x;        // 0..767
    const int d = threadIdx.x;       // 0..127
    const int sec = c >> 7, j = c & 127, h = j >> 4, l = j & 15;
    float v, b;
    if (sec == 4)      { v = Wq[d * DIM + j]; b = bq[j]; }
    else if (sec == 5) { v = Wa[d * DIM + j]; b = ba[j]; }
    else {
        const float* W1 = (sec < 2) ? Wk : Wm;
        const float* bs = (sec < 2) ? bk : bm;
        const float* W2 = (sec == 0) ? Watt0 : (sec == 1) ? Watt1
                          : (sec == 2) ? Wmsg0 : Wmsg1;
        float scale = (sec == 0) ? prior0[h] * 0.25f
                    : (sec == 1) ? prior1[h] * 0.25f : 1.f;
        float s = 0.f, sb = 0.f;
        #pragma unroll
        for (int kk = 0; kk < NC; ++kk) {
            float w2 = W2[h * 256 + kk * 16 + l];
            s  = fmaf(W1[d * DIM + h * 16 + kk], w2, s);
            sb = fmaf(bs[h * 16 + kk], w2, sb);
        }
        v = s * scale; b = sb * scale;
    }
    Wt[(size_t)c * DIM + d] = __float2bfloat16(v);
    if (d == 0) bias[c] = b;
}

// ---------------- proj: bf16 MFMA GEMM [N,128]@[128,640] ---------------------
// Persistent grid-stride kernel, 8 waves (512 thr). Each wave owns one 16-col
// tile per section; its 20 W fragments + 5 bias vectors live in REGISTERS for
// the whole kernel (no W reloads in the loop -> kills the L2-latency serial
// chain that capped v1 at 100us with VGPR_Count=44).
// x tiles (32 rows) double-buffered in LDS with a register prefetch one tile
// ahead; one barrier per iteration; direct 8B stores (D = W·x^T layout).
__global__ __launch_bounds__(512) void proj_mfma(
    const float* __restrict__ x,             // [N][128] fp32
    const __hip_bfloat16* __restrict__ Wt,   // [768][128]
    const float* __restrict__ bias,          // [768]
    __hip_bfloat16* __restrict__ kattC,      // [2N][128]
    __hip_bfloat16* __restrict__ mmsgC,      // [2N][128]
    __hip_bfloat16* __restrict__ qb)         // [N][128]
{
    __shared__ __align__(16) short xs[2][32 * DIM];   // 2 x 8 KB
    const int tid = threadIdx.x;
    const int wave = tid >> 6, lane = tid & 63;
    const int quad = lane >> 4, mcol = lane & 15;
    const int nt = N_NODES / 32;                      // 3125

    // ---- hoist W fragments + bias into registers (once) -------------------
    short8v wf[5][4];
    float4v bv[5];
    #pragma unroll
    for (int s = 0; s < 5; ++s) {
        const int c0 = s * 128 + wave * 16;
        const short* wp = (const short*)Wt + (size_t)(c0 + mcol) * DIM + quad * 8;
        #pragma unroll
        for (int kb = 0; kb < 4; ++kb)
            wf[s][kb] = *(const short8v*)(wp + kb * 32);
        bv[s] = *(const float4v*)(bias + c0 + quad * 4);
    }

    // ---- staging geometry: thread -> (row 0..31, 16B chunk 0..15) ----------
    const int srow = tid >> 4, sc8 = tid & 15;
    const int swz = ((sc8 ^ (srow & 7)) * 8);         // XOR-swizzled chunk

    int t = blockIdx.x;
    if (t >= nt) return;

    // prologue: stage tile t into buf0, prefetch tile t+G into regs
    float4v f0 = *(const float4v*)(x + (size_t)(t * 32 + srow) * DIM + sc8 * 8);
    float4v f1 = *(const float4v*)(x + (size_t)(t * 32 + srow) * DIM + sc8 * 8 + 4);
    {
        short8v sv;
        #pragma unroll
        for (int j = 0; j < 4; ++j) { sv[j] = bf16bits(f0[j]); sv[j + 4] = bf16bits(f1[j]); }
        *(short8v*)(xs[0] + srow * DIM + swz) = sv;
    }
    {
        int nn = t + PROJ_GRID;
        if (nn < nt) {
            f0 = *(const float4v*)(x + (size_t)(nn * 32 + srow) * DIM + sc8 * 8);
            f1 = *(const float4v*)(x + (size_t)(nn * 32 + srow) * DIM + sc8 * 8 + 4);
        }
    }

    int cur = 0;
    for (; t < nt; t += PROJ_GRID) {
        __syncthreads();   // buf[cur] fully staged; prev iter's reads complete

        // B fragments (x^T) for 32 rows: node = mcol (+16), k = quad*8 + j
        short8v b0[4], b1[4];
        #pragma unroll
        for (int kb = 0; kb < 4; ++kb) {
            const int ch = ((quad + kb * 4) ^ (mcol & 7)) * 8;
            b0[kb] = *(const short8v*)(xs[cur] + mcol * DIM + ch);
            b1[kb] = *(const short8v*)(xs[cur] + (mcol + 16) * DIM + ch);
        }

        const int r0 = t * 32;
        #pragma unroll
        for (int s = 0; s < 5; ++s) {
            float4v acc0 = {0.f, 0.f, 0.f, 0.f};
            float4v acc1 = {0.f, 0.f, 0.f, 0.f};
            #pragma unroll
            for (int kb = 0; kb < 4; ++kb) {
                acc0 = __builtin_amdgcn_mfma_f32_16x16x32_bf16(wf[s][kb], b0[kb], acc0, 0, 0, 0);
                acc1 = __builtin_amdgcn_mfma_f32_16x16x32_bf16(wf[s][kb], b1[kb], acc1, 0, 0, 0);
            }
            __hip_bfloat16* dst =
                (s == 0) ? kattC :
                (s == 1) ? kattC + (size_t)N_NODES * DIM :
                (s == 2) ? mmsgC :
                (s == 3) ? mmsgC + (size_t)N_NODES * DIM :
                           qb;
            short* drow0 = (short*)dst + (size_t)(r0 + mcol) * DIM + wave * 16 + quad * 4;
            short4v o0, o1;
            #pragma unroll
            for (int g = 0; g < 4; ++g) {
                o0[g] = bf16bits(acc0[g] + bv[s][g]);
                o1[g] = bf16bits(acc1[g] + bv[s][g]);
            }
            *(short4v*)drow0              = o0;
            *(short4v*)(drow0 + 16 * DIM) = o1;
        }

        // stage tile t+G (already in f0/f1) into buf[cur^1]; prefetch t+2G
        int nn = t + PROJ_GRID;
        if (nn < nt) {
            short8v sv;
            #pragma unroll
            for (int j = 0; j < 4; ++j) { sv[j] = bf16bits(f0[j]); sv[j + 4] = bf16bits(f1[j]); }
            *(short8v*)(xs[cur ^ 1] + srow * DIM + swz) = sv;
            int n2 = nn + PROJ_GRID;
            if (n2 < nt) {
                f0 = *(const float4v*)(x + (size_t)(n2 * 32 + srow) * DIM + sc8 * 8);
                f1 = *(const float4v*)(x + (size_t)(n2 * 32 + srow) * DIM + sc8 * 8 + 4);
            }
        }
        cur ^= 1;
    }
}

// ---------------- CSR build ----------------
__global__ __launch_bounds__(256) void hist_kernel(
    const int* __restrict__ dst0, const int* __restrict__ dst1,
    int* __restrict__ counts)
{
    int e = blockIdx.x * 256 + threadIdx.x;
    if (e < E_EDGES) atomicAdd(&counts[dst0[e]], 1);
    int e1 = e - E_EDGES;
    if (e1 >= 0 && e1 < E_EDGES) atomicAdd(&counts[dst1[e1]], 1);
}

__global__ __launch_bounds__(SCAN_B) void scanA_kernel(
    const int* __restrict__ counts, int* __restrict__ row_ptr,
    int* __restrict__ bsum)
{
    __shared__ int buf[2][SCAN_B];
    int i = blockIdx.x * SCAN_B + threadIdx.x;
    int v = (i < N_NODES) ? counts[i] : 0;
    int cur = 0;
    buf[0][threadIdx.x] = v;
    __syncthreads();
    #pragma unroll
    for (int off = 1; off < SCAN_B; off <<= 1) {
        int t = buf[cur][threadIdx.x];
        int add = (threadIdx.x >= off) ? buf[cur][threadIdx.x - off] : 0;
        buf[cur ^ 1][threadIdx.x] = t + add;
        cur ^= 1;
        __syncthreads();
    }
    int inc = buf[cur][threadIdx.x];
    if (i < N_NODES) row_ptr[i] = inc - v;
    if (threadIdx.x == SCAN_B - 1) bsum[blockIdx.x] = inc;
}

// parallel exclusive scan of the (<=128) block sums, single block
__global__ __launch_bounds__(128) void scanB_kernel(int* __restrict__ bsum, int nblocks)
{
    __shared__ int buf[2][128];
    int t = threadIdx.x;
    int v = (t < nblocks) ? bsum[t] : 0;
    buf[0][t] = v;
    __syncthreads();
    int cur = 0;
    #pragma unroll
    for (int off = 1; off < 128; off <<= 1) {
        int a = buf[cur][t];
        if (t >= off) a += buf[cur][t - off];
        buf[cur ^ 1][t] = a;
        cur ^= 1;
        __syncthreads();
    }
    if (t < nblocks) bsum[t] = buf[cur][t] - v;   // exclusive
}

__global__ __launch_bounds__(SCAN_B) void scanC_kernel(
    int* __restrict__ row_ptr, int* __restrict__ cursor,
    const int* __restrict__ bsum)
{
    int i = blockIdx.x * SCAN_B + threadIdx.x;
    if (i < N_NODES) {
        int r = row_ptr[i] + bsum[blockIdx.x];
        row_ptr[i] = r;
        cursor[i] = r;
    }
}

__global__ __launch_bounds__(256) void scatter_kernel(
    const int* __restrict__ src0, const int* __restrict__ dst0,
    const int* __restrict__ src1, const int* __restrict__ dst1,
    int* __restrict__ cursor, unsigned int* __restrict__ eidx)
{
    int e = blockIdx.x * 256 + threadIdx.x;
    if (e < E_EDGES) {
        int d = dst0[e];
        int pos = atomicAdd(&cursor[d], 1);
        eidx[pos] = (unsigned int)src0[e];
    }
    int e1 = e - E_EDGES;
    if (e1 >= 0 && e1 < E_EDGES) {
        int d = dst1[e1];
        int pos = atomicAdd(&cursor[d], 1);
        eidx[pos] = (unsigned int)(src1[e1] + N_NODES);
    }
}

// ---------------- aggregation: one wave per node, no atomics -----------------
// Lane owns channel pair (2*lane, 2*lane+1). Writes gelu(pooled/denom) in bf16.
__global__ __launch_bounds__(256) void agg_kernel(
    const __hip_bfloat162* __restrict__ katt,   // [2N][64] channel pairs
    const __hip_bfloat162* __restrict__ mmsg,   // [2N][64]
    const __hip_bfloat162* __restrict__ qb2,    // [N][64]
    const int* __restrict__ row_ptr, const int* __restrict__ counts,
    const unsigned int* __restrict__ eidx,
    __hip_bfloat162* __restrict__ pooled2)      // [N][64]
{
    const int wave = threadIdx.x >> 6, lane = threadIdx.x & 63;
    const int n = blockIdx.x * 4 + wave;
    if (n >= N_NODES) return;
    const int start = row_ptr[n], cnt = counts[n];
    __hip_bfloat162 qv = qb2[(size_t)n * 64 + lane];
    const float qx = __bfloat162float(qv.x), qy = __bfloat162float(qv.y);

    float accx = 0.f, accy = 0.f, den = 0.f;
    int i = 0;
    for (; i + 2 <= cnt; i += 2) {
        unsigned int r0 = eidx[start + i];
        unsigned int r1 = eidx[start + i + 1];
        __hip_bfloat162 ka0 = katt[(size_t)r0 * 64 + lane];
        __hip_bfloat162 ka1 = katt[(size_t)r1 * 64 + lane];
        __hip_bfloat162 mg0 = mmsg[(size_t)r0 * 64 + lane];
        __hip_bfloat162 mg1 = mmsg[(size_t)r1 * 64 + lane];
        float p0 = fmaf(__bfloat162float(ka0.x), qx,
                        __bfloat162float(ka0.y) * qy);
        float p1 = fmaf(__bfloat162float(ka1.x), qx,
                        __bfloat162float(ka1.y) * qy);
        p0 += __shfl_xor(p0, 1, 64); p0 += __shfl_xor(p0, 2, 64); p0 += __shfl_xor(p0, 4, 64);
        p1 += __shfl_xor(p1, 1, 64); p1 += __shfl_xor(p1, 2, 64); p1 += __shfl_xor(p1, 4, 64);
        float e0 = __expf(p0), e1 = __expf(p1);
        accx = fmaf(e0, __bfloat162float(mg0.x), accx);
        accy = fmaf(e0, __bfloat162float(mg0.y), accy);
        accx = fmaf(e1, __bfloat162float(mg1.x), accx);
        accy = fmaf(e1, __bfloat162float(mg1.y), accy);
        den += e0 + e1;
    }
    if (i < cnt) {
        unsigned int r0 = eidx[start + i];
        __hip_bfloat162 ka0 = katt[(size_t)r0 * 64 + lane];
        __hip_bfloat162 mg0 = mmsg[(size_t)r0 * 64 + lane];
        float p0 = fmaf(__bfloat162float(ka0.x), qx,
                        __bfloat162float(ka0.y) * qy);
        p0 += __shfl_xor(p0, 1, 64); p0 += __shfl_xor(p0, 2, 64); p0 += __shfl_xor(p0, 4, 64);
        float e0 = __expf(p0);
        accx = fmaf(e0, __bfloat162float(mg0.x), accx);
        accy = fmaf(e0, __bfloat162float(mg0.y), accy);
        den += e0;
    }

    float vx = 0.f, vy = 0.f;
    if (den > 0.f) { vx = accx / den; vy = accy / den; }
    vx = 0.5f * vx * (1.f + erff(vx * 0.70710678118654752f));
    vy = 0.5f * vy * (1.f + erff(vy * 0.70710678118654752f));
    __hip_bfloat162 o; o.x = __float2bfloat16(vx); o.y = __float2bfloat16(vy);
    pooled2[(size_t)n * 64 + lane] = o;
}

// ---------------- final: MFMA GEMM(Wa) -> skip -> LayerNorm ------------------
__global__ __launch_bounds__(256) void final_mfma(
    const __hip_bfloat16* __restrict__ pooled,  // [N][128] bf16, gelu applied
    const __hip_bfloat16* __restrict__ Wt,      // [768][128]; rows 640.. = Wa^T
    const float* __restrict__ bias,             // [768]; 640.. = ba
    const float* __restrict__ x,
    const float* __restrict__ skip, const float* __restrict__ gamma,
    const float* __restrict__ beta, float* __restrict__ out)
{
    __shared__ float hs[32][DIM];
    const int wave = threadIdx.x >> 6, lane = threadIdx.x & 63;
    const int quad = lane >> 4, mcol = lane & 15;
    const int r0 = blockIdx.x * 32;

    short8v a0[4], a1[4];
    const short* pp0 = (const short*)pooled + (size_t)(r0 + mcol) * DIM + quad * 8;
    const short* pp1 = pp0 + 16 * DIM;
    #pragma unroll
    for (int kb = 0; kb < 4; ++kb) {
        a0[kb] = *(const short8v*)(pp0 + kb * 32);
        a1[kb] = *(const short8v*)(pp1 + kb * 32);
    }
    const float alpha = 1.f / (1.f + expf(-skip[0]));

    #pragma unroll
    for (int t = 0; t < 2; ++t) {
        const int c0 = wave * 32 + t * 16;
        const short* wp = (const short*)Wt + (size_t)(640 + c0 + mcol) * DIM + quad * 8;
        float4v acc0 = {0.f, 0.f, 0.f, 0.f};
        float4v acc1 = {0.f, 0.f, 0.f, 0.f};
        #pragma unroll
        for (int kb = 0; kb < 4; ++kb) {
            short8v bfr = *(const short8v*)(wp + kb * 32);
            acc0 = __builtin_amdgcn_mfma_f32_16x16x32_bf16(a0[kb], bfr, acc0, 0, 0, 0);
            acc1 = __builtin_amdgcn_mfma_f32_16x16x32_bf16(a1[kb], bfr, acc1, 0, 0, 0);
        }
        const float bcol = bias[640 + c0 + mcol];
        const int cc = c0 + mcol;
        const int rq = quad * 4;
        #pragma unroll
        for (int g = 0; g < 4; ++g) {
            int rA = rq + g, rB = rq + 16 + g;
            hs[rA][cc] = alpha * (acc0[g] + bcol)
                       + (1.f - alpha) * x[(size_t)(r0 + rA) * DIM + cc];
            hs[rB][cc] = alpha * (acc1[g] + bcol)
                       + (1.f - alpha) * x[(size_t)(r0 + rB) * DIM + cc];
        }
    }
    __syncthreads();

    float gam0 = gamma[lane], gam1 = gamma[lane + 64];
    float bet0 = beta[lane],  bet1 = beta[lane + 64];
    for (int r = wave; r < 32; r += 4) {
        int row = r0 + r;
        float v0 = hs[r][lane], v1 = hs[r][lane + 64];
        float s = v0 + v1, s2 = v0 * v0 + v1 * v1;
        #pragma unroll
        for (int off = 1; off < 64; off <<= 1) {
            s  += __shfl_xor(s,  off, 64);
            s2 += __shfl_xor(s2, off, 64);
        }
        float mu = s * (1.f / 128.f);
        float var = s2 * (1.f / 128.f) - mu * mu;
        float rstd = rsqrtf(var + LN_EPS);
        out[(size_t)row * DIM + lane]      = (v0 - mu) * rstd * gam0 + bet0;
        out[(size_t)row * DIM + lane + 64] = (v1 - mu) * rstd * gam1 + bet1;
    }
}

extern "C" void kernel_launch(void* const* d_in, const int* in_sizes, int n_in,
                              void* d_out, int out_size, void* d_ws, size_t ws_size,
                              hipStream_t stream) {
    const float* x     = (const float*)d_in[0];
    const int*   src0  = (const int*)d_in[1];
    const int*   dst0  = (const int*)d_in[2];
    const int*   src1  = (const int*)d_in[3];
    const int*   dst1  = (const int*)d_in[4];
    const float* Wk    = (const float*)d_in[5];
    const float* bk    = (const float*)d_in[6];
    const float* Wm    = (const float*)d_in[7];
    const float* bm    = (const float*)d_in[8];
    const float* Wq    = (const float*)d_in[9];
    const float* bq    = (const float*)d_in[10];
    const float* Wa    = (const float*)d_in[11];
    const float* ba    = (const float*)d_in[12];
    const float* Watt0 = (const float*)d_in[13];
    const float* Wmsg0 = (const float*)d_in[14];
    const float* Watt1 = (const float*)d_in[15];
    const float* Wmsg1 = (const float*)d_in[16];
    const float* prior0= (const float*)d_in[17];
    const float* prior1= (const float*)d_in[18];
    const float* skip  = (const float*)d_in[19];
    const float* gamma = (const float*)d_in[20];
    const float* beta  = (const float*)d_in[21];
    float* out = (float*)d_out;

    const size_t nd = (size_t)N_NODES * DIM;
    // Workspace (~158 MB):
    //   Wt [768*128 bf16] | bias [768 f32] | kattC [2nd bf16] | mmsgC [2nd bf16]
    //   | qb [nd bf16] | pooled [nd bf16] | counts/row_ptr/cursor [N i32]
    //   | bsum [128 i32] | eidx [2E u32]
    char* wsb = (char*)d_ws;
    __hip_bfloat16* Wt    = (__hip_bfloat16*)wsb;  wsb += (size_t)768 * DIM * 2;
    float* bias           = (float*)wsb;           wsb += 768 * 4;
    __hip_bfloat16* kattC = (__hip_bfloat16*)wsb;  wsb += 2 * nd * 2;
    __hip_bfloat16* mmsgC = (__hip_bfloat16*)wsb;  wsb += 2 * nd * 2;
    __hip_bfloat16* qb    = (__hip_bfloat16*)wsb;  wsb += nd * 2;
    __hip_bfloat16* pooled= (__hip_bfloat16*)wsb;  wsb += nd * 2;
    int* counts  = (int*)wsb;                      wsb += (size_t)N_NODES * 4;
    int* row_ptr = (int*)wsb;                      wsb += (size_t)N_NODES * 4;
    int* cursor  = (int*)wsb;                      wsb += (size_t)N_NODES * 4;
    int* bsum    = (int*)wsb;                      wsb += 128 * 4;
    unsigned int* eidx = (unsigned int*)wsb;

    hipMemsetAsync(counts, 0, (size_t)N_NODES * 4, stream);

    const int scan_blocks = (N_NODES + SCAN_B - 1) / SCAN_B;   // 98
    const int edge_blocks = (2 * E_EDGES + 255) / 256;         // 3125

    // CSR chain (independent of projections)
    hist_kernel<<<dim3(edge_blocks), dim3(256), 0, stream>>>(dst0, dst1, counts);
    scanA_kernel<<<dim3(scan_blocks), dim3(SCAN_B), 0, stream>>>(counts, row_ptr, bsum);
    scanB_kernel<<<dim3(1), dim3(128), 0, stream>>>(bsum, scan_blocks);
    scanC_kernel<<<dim3(scan_blocks), dim3(SCAN_B), 0, stream>>>(row_ptr, cursor, bsum);
    scatter_kernel<<<dim3(edge_blocks), dim3(256), 0, stream>>>(
        src0, dst0, src1, dst1, cursor, eidx);

    // Projections
    fuse_weights<<<dim3(768), dim3(128), 0, stream>>>(
        Wk, bk, Wm, bm, Wq, bq, Wa, ba,
        Watt0, Wmsg0, Watt1, Wmsg1, prior0, prior1, Wt, bias);
    proj_mfma<<<dim3(PROJ_GRID), dim3(512), 0, stream>>>(
        x, Wt, bias, kattC, mmsgC, qb);

    agg_kernel<<<dim3((N_NODES + 3) / 4), dim3(256), 0, stream>>>(
        (const __hip_bfloat162*)kattC, (const __hip_bfloat162*)mmsgC,
        (const __hip_bfloat162*)qb, row_ptr, counts, eidx,
        (__hip_bfloat162*)pooled);

    final_mfma<<<dim3(N_NODES / 32), dim3(256), 0, stream>>>(
        pooled, Wt, bias, x, skip, gamma, beta, out);
}

// Round 4
// 370.516 us; speedup vs baseline: 1.1178x; 1.0063x over previous
//
#include <hip/hip_runtime.h>
#include <hip/hip_bf16.h>
#include <math.h>

#define N_NODES 100000
#define DIM 128
#define NH 8
#define NC 16
#define E_EDGES 400000
#define LN_EPS 1e-3f
#define SCAN_B 1024
#define PROJ_GRID 512

typedef __attribute__((ext_vector_type(8))) short short8v;
typedef __attribute__((ext_vector_type(4))) short short4v;
typedef __attribute__((ext_vector_type(4))) float float4v;

__device__ __forceinline__ short bf16bits(float v) {
    __hip_bfloat16 b = __float2bfloat16(v);
    return *(short*)&b;
}

// unpack a uint holding 2 bf16 (lo, hi) into 2 floats
__device__ __forceinline__ void bf2x2(unsigned v, float& a, float& b) {
    a = __uint_as_float(v << 16);
    b = __uint_as_float(v & 0xffff0000u);
}

// ---------------- fused transposed weights (bf16) + fused biases -------------
// Wt[c][d], c in [0,768): sections of 128 cols:
//  0: Wk·BD(Watt0)·prior0/sqrt(C)   1: Wk·BD(Watt1)·prior1/sqrt(C)
//  2: Wm·BD(Wmsg0)                  3: Wm·BD(Wmsg1)
//  4: Wq                            5: Wa
__global__ __launch_bounds__(128) void fuse_weights(
    const float* __restrict__ Wk, const float* __restrict__ bk,
    const float* __restrict__ Wm, const float* __restrict__ bm,
    const float* __restrict__ Wq, const float* __restrict__ bq,
    const float* __restrict__ Wa, const float* __restrict__ ba,
    const float* __restrict__ Watt0, const float* __restrict__ Wmsg0,
    const float* __restrict__ Watt1, const float* __restrict__ Wmsg1,
    const float* __restrict__ prior0, const float* __restrict__ prior1,
    __hip_bfloat16* __restrict__ Wt, float* __restrict__ bias)
{
    const int c = blockIdx.x;        // 0..767
    const int d = threadIdx.x;       // 0..127
    const int sec = c >> 7, j = c & 127, h = j >> 4, l = j & 15;
    float v, b;
    if (sec == 4)      { v = Wq[d * DIM + j]; b = bq[j]; }
    else if (sec == 5) { v = Wa[d * DIM + j]; b = ba[j]; }
    else {
        const float* W1 = (sec < 2) ? Wk : Wm;
        const float* bs = (sec < 2) ? bk : bm;
        const float* W2 = (sec == 0) ? Watt0 : (sec == 1) ? Watt1
                          : (sec == 2) ? Wmsg0 : Wmsg1;
        float scale = (sec == 0) ? prior0[h] * 0.25f
                    : (sec == 1) ? prior1[h] * 0.25f : 1.f;
        float s = 0.f, sb = 0.f;
        #pragma unroll
        for (int kk = 0; kk < NC; ++kk) {
            float w2 = W2[h * 256 + kk * 16 + l];
            s  = fmaf(W1[d * DIM + h * 16 + kk], w2, s);
            sb = fmaf(bs[h * 16 + kk], w2, sb);
        }
        v = s * scale; b = sb * scale;
    }
    Wt[(size_t)c * DIM + d] = __float2bfloat16(v);
    if (d == 0) bias[c] = b;
}

// ---------------- proj: bf16 MFMA GEMM [N,128]@[128,640] ---------------------
// Persistent grid-stride kernel, 8 waves (512 thr). W fragments + bias live in
// registers for the whole kernel. x tiles double-buffered in LDS.
// Sections 0-3 now write into the INTERLEAVED km layout: km[2N][256] where
// row r = katt_row(128) | mmsg_row(128) -> agg gathers ONE 512B burst/edge.
__global__ __launch_bounds__(512) void proj_mfma(
    const float* __restrict__ x,             // [N][128] fp32
    const __hip_bfloat16* __restrict__ Wt,   // [768][128]
    const float* __restrict__ bias,          // [768]
    __hip_bfloat16* __restrict__ km,         // [2N][256] katt|mmsg interleaved
    __hip_bfloat16* __restrict__ qb)         // [N][128]
{
    __shared__ __align__(16) short xs[2][32 * DIM];   // 2 x 8 KB
    const int tid = threadIdx.x;
    const int wave = tid >> 6, lane = tid & 63;
    const int quad = lane >> 4, mcol = lane & 15;
    const int nt = N_NODES / 32;                      // 3125

    // ---- hoist W fragments + bias into registers (once) -------------------
    short8v wf[5][4];
    float4v bv[5];
    #pragma unroll
    for (int s = 0; s < 5; ++s) {
        const int c0 = s * 128 + wave * 16;
        const short* wp = (const short*)Wt + (size_t)(c0 + mcol) * DIM + quad * 8;
        #pragma unroll
        for (int kb = 0; kb < 4; ++kb)
            wf[s][kb] = *(const short8v*)(wp + kb * 32);
        bv[s] = *(const float4v*)(bias + c0 + quad * 4);
    }

    // ---- staging geometry: thread -> (row 0..31, 16B chunk 0..15) ----------
    const int srow = tid >> 4, sc8 = tid & 15;
    const int swz = ((sc8 ^ (srow & 7)) * 8);         // XOR-swizzled chunk

    int t = blockIdx.x;
    if (t >= nt) return;

    // prologue: stage tile t into buf0, prefetch tile t+G into regs
    float4v f0 = *(const float4v*)(x + (size_t)(t * 32 + srow) * DIM + sc8 * 8);
    float4v f1 = *(const float4v*)(x + (size_t)(t * 32 + srow) * DIM + sc8 * 8 + 4);
    {
        short8v sv;
        #pragma unroll
        for (int j = 0; j < 4; ++j) { sv[j] = bf16bits(f0[j]); sv[j + 4] = bf16bits(f1[j]); }
        *(short8v*)(xs[0] + srow * DIM + swz) = sv;
    }
    {
        int nn = t + PROJ_GRID;
        if (nn < nt) {
            f0 = *(const float4v*)(x + (size_t)(nn * 32 + srow) * DIM + sc8 * 8);
            f1 = *(const float4v*)(x + (size_t)(nn * 32 + srow) * DIM + sc8 * 8 + 4);
        }
    }

    int cur = 0;
    for (; t < nt; t += PROJ_GRID) {
        __syncthreads();   // buf[cur] fully staged; prev iter's reads complete

        // B fragments (x^T) for 32 rows: node = mcol (+16), k = quad*8 + j
        short8v b0[4], b1[4];
        #pragma unroll
        for (int kb = 0; kb < 4; ++kb) {
            const int ch = ((quad + kb * 4) ^ (mcol & 7)) * 8;
            b0[kb] = *(const short8v*)(xs[cur] + mcol * DIM + ch);
            b1[kb] = *(const short8v*)(xs[cur] + (mcol + 16) * DIM + ch);
        }

        const int r0 = t * 32;
        #pragma unroll
        for (int s = 0; s < 5; ++s) {
            float4v acc0 = {0.f, 0.f, 0.f, 0.f};
            float4v acc1 = {0.f, 0.f, 0.f, 0.f};
            #pragma unroll
            for (int kb = 0; kb < 4; ++kb) {
                acc0 = __builtin_amdgcn_mfma_f32_16x16x32_bf16(wf[s][kb], b0[kb], acc0, 0, 0, 0);
                acc1 = __builtin_amdgcn_mfma_f32_16x16x32_bf16(wf[s][kb], b1[kb], acc1, 0, 0, 0);
            }
            short4v o0, o1;
            #pragma unroll
            for (int g = 0; g < 4; ++g) {
                o0[g] = bf16bits(acc0[g] + bv[s][g]);
                o1[g] = bf16bits(acc1[g] + bv[s][g]);
            }
            if (s < 4) {
                // km row = node + (edge-set? N:0); col half = (katt?0:128)
                size_t row = (size_t)(r0 + mcol) + ((s & 1) ? (size_t)N_NODES : 0);
                short* dp = (short*)km + row * 256 + ((s & 2) ? 128 : 0)
                          + wave * 16 + quad * 4;
                *(short4v*)dp              = o0;
                *(short4v*)(dp + 16 * 256) = o1;
            } else {
                short* dp = (short*)qb + (size_t)(r0 + mcol) * DIM
                          + wave * 16 + quad * 4;
                *(short4v*)dp              = o0;
                *(short4v*)(dp + 16 * DIM) = o1;
            }
        }

        // stage tile t+G (already in f0/f1) into buf[cur^1]; prefetch t+2G
        int nn = t + PROJ_GRID;
        if (nn < nt) {
            short8v sv;
            #pragma unroll
            for (int j = 0; j < 4; ++j) { sv[j] = bf16bits(f0[j]); sv[j + 4] = bf16bits(f1[j]); }
            *(short8v*)(xs[cur ^ 1] + srow * DIM + swz) = sv;
            int n2 = nn + PROJ_GRID;
            if (n2 < nt) {
                f0 = *(const float4v*)(x + (size_t)(n2 * 32 + srow) * DIM + sc8 * 8);
                f1 = *(const float4v*)(x + (size_t)(n2 * 32 + srow) * DIM + sc8 * 8 + 4);
            }
        }
        cur ^= 1;
    }
}

// ---------------- CSR build ----------------
__global__ __launch_bounds__(256) void hist_kernel(
    const int* __restrict__ dst0, const int* __restrict__ dst1,
    int* __restrict__ counts)
{
    int e = blockIdx.x * 256 + threadIdx.x;
    if (e < E_EDGES) atomicAdd(&counts[dst0[e]], 1);
    int e1 = e - E_EDGES;
    if (e1 >= 0 && e1 < E_EDGES) atomicAdd(&counts[dst1[e1]], 1);
}

__global__ __launch_bounds__(SCAN_B) void scanA_kernel(
    const int* __restrict__ counts, int* __restrict__ row_ptr,
    int* __restrict__ bsum)
{
    __shared__ int buf[2][SCAN_B];
    int i = blockIdx.x * SCAN_B + threadIdx.x;
    int v = (i < N_NODES) ? counts[i] : 0;
    int cur = 0;
    buf[0][threadIdx.x] = v;
    __syncthreads();
    #pragma unroll
    for (int off = 1; off < SCAN_B; off <<= 1) {
        int t = buf[cur][threadIdx.x];
        int add = (threadIdx.x >= off) ? buf[cur][threadIdx.x - off] : 0;
        buf[cur ^ 1][threadIdx.x] = t + add;
        cur ^= 1;
        __syncthreads();
    }
    int inc = buf[cur][threadIdx.x];
    if (i < N_NODES) row_ptr[i] = inc - v;
    if (threadIdx.x == SCAN_B - 1) bsum[blockIdx.x] = inc;
}

// parallel exclusive scan of the (<=128) block sums, single block
__global__ __launch_bounds__(128) void scanB_kernel(int* __restrict__ bsum, int nblocks)
{
    __shared__ int buf[2][128];
    int t = threadIdx.x;
    int v = (t < nblocks) ? bsum[t] : 0;
    buf[0][t] = v;
    __syncthreads();
    int cur = 0;
    #pragma unroll
    for (int off = 1; off < 128; off <<= 1) {
        int a = buf[cur][t];
        if (t >= off) a += buf[cur][t - off];
        buf[cur ^ 1][t] = a;
        cur ^= 1;
        __syncthreads();
    }
    if (t < nblocks) bsum[t] = buf[cur][t] - v;   // exclusive
}

__global__ __launch_bounds__(SCAN_B) void scanC_kernel(
    int* __restrict__ row_ptr, int* __restrict__ cursor,
    const int* __restrict__ bsum)
{
    int i = blockIdx.x * SCAN_B + threadIdx.x;
    if (i < N_NODES) {
        int r = row_ptr[i] + bsum[blockIdx.x];
        row_ptr[i] = r;
        cursor[i] = r;
    }
}

__global__ __launch_bounds__(256) void scatter_kernel(
    const int* __restrict__ src0, const int* __restrict__ dst0,
    const int* __restrict__ src1, const int* __restrict__ dst1,
    int* __restrict__ cursor, unsigned int* __restrict__ eidx)
{
    int e = blockIdx.x * 256 + threadIdx.x;
    if (e < E_EDGES) {
        int d = dst0[e];
        int pos = atomicAdd(&cursor[d], 1);
        eidx[pos] = (unsigned int)src0[e];
    }
    int e1 = e - E_EDGES;
    if (e1 >= 0 && e1 < E_EDGES) {
        int d = dst1[e1];
        int pos = atomicAdd(&cursor[d], 1);
        eidx[pos] = (unsigned int)(src1[e1] + N_NODES);
    }
}

// ---------------- aggregation: one wave per node, no atomics -----------------
// km row per edge = ONE contiguous 512B gather. Lanes 0-31 own katt (4 ch each,
// head = lane>>2); lanes 32-63 own mmsg. One set of bf16 converts serves both
// the q-dot and the accumulation. Score reduce = 2 quad shuffles; weight
// crosses halves via shfl_xor 32. 4-edge unroll -> 4 gathers in flight.
__global__ __launch_bounds__(256) void agg_kernel(
    const uint2* __restrict__ km,      // [2N][64] uint2 (katt|mmsg rows)
    const uint2* __restrict__ qv,      // [N][32] uint2
    const int* __restrict__ row_ptr, const int* __restrict__ counts,
    const unsigned int* __restrict__ eidx,
    unsigned int* __restrict__ pooled) // [N][64] uint (2 bf16 each)
{
    const int wave = threadIdx.x >> 6, lane = threadIdx.x & 63;
    const int n = blockIdx.x * 4 + wave;
    if (n >= N_NODES) return;
    const int start = row_ptr[n], cnt = counts[n];
    const int low = lane & 31;

    uint2 qu = qv[(size_t)n * 32 + low];
    float q0, q1, q2, q3;
    bf2x2(qu.x, q0, q1); bf2x2(qu.y, q2, q3);

    float a0 = 0.f, a1 = 0.f, a2 = 0.f, a3 = 0.f, den = 0.f;

#define EDGE_ACC(u)                                                          \
    {                                                                        \
        float c0, c1, c2, c3;                                                \
        bf2x2((u).x, c0, c1); bf2x2((u).y, c2, c3);                          \
        float p = fmaf(c3, q3, fmaf(c2, q2, fmaf(c1, q1, c0 * q0)));         \
        p += __shfl_xor(p, 1, 64); p += __shfl_xor(p, 2, 64);                \
        float e = __expf(p);                                                 \
        den += e;                                                            \
        float eb = __shfl_xor(e, 32, 64);                                    \
        a0 = fmaf(eb, c0, a0); a1 = fmaf(eb, c1, a1);                        \
        a2 = fmaf(eb, c2, a2); a3 = fmaf(eb, c3, a3);                        \
    }

    int i = 0;
    for (; i + 4 <= cnt; i += 4) {
        unsigned r0i = eidx[start + i];
        unsigned r1i = eidx[start + i + 1];
        unsigned r2i = eidx[start + i + 2];
        unsigned r3i = eidx[start + i + 3];
        uint2 u0 = km[(size_t)r0i * 64 + lane];
        uint2 u1 = km[(size_t)r1i * 64 + lane];
        uint2 u2 = km[(size_t)r2i * 64 + lane];
        uint2 u3 = km[(size_t)r3i * 64 + lane];
        EDGE_ACC(u0); EDGE_ACC(u1); EDGE_ACC(u2); EDGE_ACC(u3);
    }
    for (; i < cnt; ++i) {
        unsigned r0i = eidx[start + i];
        uint2 u0 = km[(size_t)r0i * 64 + lane];
        EDGE_ACC(u0);
    }
#undef EDGE_ACC

    // lanes 32-63 hold mmsg accumulators; pull den from mirror lane
    float denb = __shfl_xor(den, 32, 64);
    float v0 = 0.f, v1 = 0.f, v2 = 0.f, v3 = 0.f;
    if (denb > 0.f) {
        float inv = 1.f / denb;
        v0 = a0 * inv; v1 = a1 * inv; v2 = a2 * inv; v3 = a3 * inv;
    }
    v0 = 0.5f * v0 * (1.f + erff(v0 * 0.70710678118654752f));
    v1 = 0.5f * v1 * (1.f + erff(v1 * 0.70710678118654752f));
    v2 = 0.5f * v2 * (1.f + erff(v2 * 0.70710678118654752f));
    v3 = 0.5f * v3 * (1.f + erff(v3 * 0.70710678118654752f));

    if (lane >= 32) {
        unsigned plo = ((unsigned)(unsigned short)bf16bits(v0))
                     | ((unsigned)(unsigned short)bf16bits(v1) << 16);
        unsigned phi = ((unsigned)(unsigned short)bf16bits(v2))
                     | ((unsigned)(unsigned short)bf16bits(v3) << 16);
        pooled[(size_t)n * 64 + (lane - 32) * 2]     = plo;
        pooled[(size_t)n * 64 + (lane - 32) * 2 + 1] = phi;
    }
}

// ---------------- final: MFMA GEMM(Wa) -> skip -> LayerNorm ------------------
__global__ __launch_bounds__(256) void final_mfma(
    const __hip_bfloat16* __restrict__ pooled,  // [N][128] bf16, gelu applied
    const __hip_bfloat16* __restrict__ Wt,      // [768][128]; rows 640.. = Wa^T
    const float* __restrict__ bias,             // [768]; 640.. = ba
    const float* __restrict__ x,
    const float* __restrict__ skip, const float* __restrict__ gamma,
    const float* __restrict__ beta, float* __restrict__ out)
{
    __shared__ float hs[32][DIM];
    const int wave = threadIdx.x >> 6, lane = threadIdx.x & 63;
    const int quad = lane >> 4, mcol = lane & 15;
    const int r0 = blockIdx.x * 32;

    short8v a0[4], a1[4];
    const short* pp0 = (const short*)pooled + (size_t)(r0 + mcol) * DIM + quad * 8;
    const short* pp1 = pp0 + 16 * DIM;
    #pragma unroll
    for (int kb = 0; kb < 4; ++kb) {
        a0[kb] = *(const short8v*)(pp0 + kb * 32);
        a1[kb] = *(const short8v*)(pp1 + kb * 32);
    }
    const float alpha = 1.f / (1.f + expf(-skip[0]));

    #pragma unroll
    for (int t = 0; t < 2; ++t) {
        const int c0 = wave * 32 + t * 16;
        const short* wp = (const short*)Wt + (size_t)(640 + c0 + mcol) * DIM + quad * 8;
        float4v acc0 = {0.f, 0.f, 0.f, 0.f};
        float4v acc1 = {0.f, 0.f, 0.f, 0.f};
        #pragma unroll
        for (int kb = 0; kb < 4; ++kb) {
            short8v bfr = *(const short8v*)(wp + kb * 32);
            acc0 = __builtin_amdgcn_mfma_f32_16x16x32_bf16(a0[kb], bfr, acc0, 0, 0, 0);
            acc1 = __builtin_amdgcn_mfma_f32_16x16x32_bf16(a1[kb], bfr, acc1, 0, 0, 0);
        }
        const float bcol = bias[640 + c0 + mcol];
        const int cc = c0 + mcol;
        const int rq = quad * 4;
        #pragma unroll
        for (int g = 0; g < 4; ++g) {
            int rA = rq + g, rB = rq + 16 + g;
            hs[rA][cc] = alpha * (acc0[g] + bcol)
                       + (1.f - alpha) * x[(size_t)(r0 + rA) * DIM + cc];
            hs[rB][cc] = alpha * (acc1[g] + bcol)
                       + (1.f - alpha) * x[(size_t)(r0 + rB) * DIM + cc];
        }
    }
    __syncthreads();

    float gam0 = gamma[lane], gam1 = gamma[lane + 64];
    float bet0 = beta[lane],  bet1 = beta[lane + 64];
    for (int r = wave; r < 32; r += 4) {
        int row = r0 + r;
        float v0 = hs[r][lane], v1 = hs[r][lane + 64];
        float s = v0 + v1, s2 = v0 * v0 + v1 * v1;
        #pragma unroll
        for (int off = 1; off < 64; off <<= 1) {
            s  += __shfl_xor(s,  off, 64);
            s2 += __shfl_xor(s2, off, 64);
        }
        float mu = s * (1.f / 128.f);
        float var = s2 * (1.f / 128.f) - mu * mu;
        float rstd = rsqrtf(var + LN_EPS);
        out[(size_t)row * DIM + lane]      = (v0 - mu) * rstd * gam0 + bet0;
        out[(size_t)row * DIM + lane + 64] = (v1 - mu) * rstd * gam1 + bet1;
    }
}

extern "C" void kernel_launch(void* const* d_in, const int* in_sizes, int n_in,
                              void* d_out, int out_size, void* d_ws, size_t ws_size,
                              hipStream_t stream) {
    const float* x     = (const float*)d_in[0];
    const int*   src0  = (const int*)d_in[1];
    const int*   dst0  = (const int*)d_in[2];
    const int*   src1  = (const int*)d_in[3];
    const int*   dst1  = (const int*)d_in[4];
    const float* Wk    = (const float*)d_in[5];
    const float* bk    = (const float*)d_in[6];
    const float* Wm    = (const float*)d_in[7];
    const float* bm    = (const float*)d_in[8];
    const float* Wq    = (const float*)d_in[9];
    const float* bq    = (const float*)d_in[10];
    const float* Wa    = (const float*)d_in[11];
    const float* ba    = (const float*)d_in[12];
    const float* Watt0 = (const float*)d_in[13];
    const float* Wmsg0 = (const float*)d_in[14];
    const float* Watt1 = (const float*)d_in[15];
    const float* Wmsg1 = (const float*)d_in[16];
    const float* prior0= (const float*)d_in[17];
    const float* prior1= (const float*)d_in[18];
    const float* skip  = (const float*)d_in[19];
    const float* gamma = (const float*)d_in[20];
    const float* beta  = (const float*)d_in[21];
    float* out = (float*)d_out;

    const size_t nd = (size_t)N_NODES * DIM;
    // Workspace (~158 MB):
    //   Wt [768*128 bf16] | bias [768 f32] | km [2N*256 bf16 interleaved]
    //   | qb [nd bf16] | pooled [nd bf16] | counts/row_ptr/cursor [N i32]
    //   | bsum [128 i32] | eidx [2E u32]
    char* wsb = (char*)d_ws;
    __hip_bfloat16* Wt    = (__hip_bfloat16*)wsb;  wsb += (size_t)768 * DIM * 2;
    float* bias           = (float*)wsb;           wsb += 768 * 4;
    __hip_bfloat16* km    = (__hip_bfloat16*)wsb;  wsb += (size_t)2 * N_NODES * 256 * 2;
    __hip_bfloat16* qb    = (__hip_bfloat16*)wsb;  wsb += nd * 2;
    __hip_bfloat16* pooled= (__hip_bfloat16*)wsb;  wsb += nd * 2;
    int* counts  = (int*)wsb;                      wsb += (size_t)N_NODES * 4;
    int* row_ptr = (int*)wsb;                      wsb += (size_t)N_NODES * 4;
    int* cursor  = (int*)wsb;                      wsb += (size_t)N_NODES * 4;
    int* bsum    = (int*)wsb;                      wsb += 128 * 4;
    unsigned int* eidx = (unsigned int*)wsb;

    hipMemsetAsync(counts, 0, (size_t)N_NODES * 4, stream);

    const int scan_blocks = (N_NODES + SCAN_B - 1) / SCAN_B;   // 98
    const int edge_blocks = (2 * E_EDGES + 255) / 256;         // 3125

    // CSR chain (independent of projections)
    hist_kernel<<<dim3(edge_blocks), dim3(256), 0, stream>>>(dst0, dst1, counts);
    scanA_kernel<<<dim3(scan_blocks), dim3(SCAN_B), 0, stream>>>(counts, row_ptr, bsum);
    scanB_kernel<<<dim3(1), dim3(128), 0, stream>>>(bsum, scan_blocks);
    scanC_kernel<<<dim3(scan_blocks), dim3(SCAN_B), 0, stream>>>(row_ptr, cursor, bsum);
    scatter_kernel<<<dim3(edge_blocks), dim3(256), 0, stream>>>(
        src0, dst0, src1, dst1, cursor, eidx);

    // Projections
    fuse_weights<<<dim3(768), dim3(128), 0, stream>>>(
        Wk, bk, Wm, bm, Wq, bq, Wa, ba,
        Watt0, Wmsg0, Watt1, Wmsg1, prior0, prior1, Wt, bias);
    proj_mfma<<<dim3(PROJ_GRID), dim3(512), 0, stream>>>(
        x, Wt, bias, km, qb);

    agg_kernel<<<dim3((N_NODES + 3) / 4), dim3(256), 0, stream>>>(
        (const uint2*)km, (const uint2*)qb, row_ptr, counts, eidx,
        (unsigned int*)pooled);

    final_mfma<<<dim3(N_NODES / 32), dim3(256), 0, stream>>>(
        pooled, Wt, bias, x, skip, gamma, beta, out);
}

// Round 5
// 357.432 us; speedup vs baseline: 1.1587x; 1.0366x over previous
//
#include <hip/hip_runtime.h>
#include <hip/hip_bf16.h>
#include <math.h>

#define N_NODES 100000
#define DIM 128
#define NH 8
#define NC 16
#define E_EDGES 400000
#define LN_EPS 1e-3f
#define SCAN_B 1024
#define PROJ_GRID 512

typedef __attribute__((ext_vector_type(8))) short short8v;
typedef __attribute__((ext_vector_type(4))) short short4v;
typedef __attribute__((ext_vector_type(4))) float float4v;

__device__ __forceinline__ short bf16bits(float v) {
    __hip_bfloat16 b = __float2bfloat16(v);
    return *(short*)&b;
}

// unpack a uint holding 2 bf16 (lo, hi) into 2 floats
__device__ __forceinline__ void bf2x2(unsigned v, float& a, float& b) {
    a = __uint_as_float(v << 16);
    b = __uint_as_float(v & 0xffff0000u);
}

// ---------------- fused transposed weights (bf16) + fused biases -------------
// Wt[c][d], c in [0,768): sections of 128 cols:
//  0: Wk·BD(Watt0)·prior0/sqrt(C)   1: Wk·BD(Watt1)·prior1/sqrt(C)
//  2: Wm·BD(Wmsg0)                  3: Wm·BD(Wmsg1)
//  4: Wq                            5: Wa
__global__ __launch_bounds__(128) void fuse_weights(
    const float* __restrict__ Wk, const float* __restrict__ bk,
    const float* __restrict__ Wm, const float* __restrict__ bm,
    const float* __restrict__ Wq, const float* __restrict__ bq,
    const float* __restrict__ Wa, const float* __restrict__ ba,
    const float* __restrict__ Watt0, const float* __restrict__ Wmsg0,
    const float* __restrict__ Watt1, const float* __restrict__ Wmsg1,
    const float* __restrict__ prior0, const float* __restrict__ prior1,
    __hip_bfloat16* __restrict__ Wt, float* __restrict__ bias)
{
    const int c = blockIdx.x;        // 0..767
    const int d = threadIdx.x;       // 0..127
    const int sec = c >> 7, j = c & 127, h = j >> 4, l = j & 15;
    float v, b;
    if (sec == 4)      { v = Wq[d * DIM + j]; b = bq[j]; }
    else if (sec == 5) { v = Wa[d * DIM + j]; b = ba[j]; }
    else {
        const float* W1 = (sec < 2) ? Wk : Wm;
        const float* bs = (sec < 2) ? bk : bm;
        const float* W2 = (sec == 0) ? Watt0 : (sec == 1) ? Watt1
                          : (sec == 2) ? Wmsg0 : Wmsg1;
        float scale = (sec == 0) ? prior0[h] * 0.25f
                    : (sec == 1) ? prior1[h] * 0.25f : 1.f;
        float s = 0.f, sb = 0.f;
        #pragma unroll
        for (int kk = 0; kk < NC; ++kk) {
            float w2 = W2[h * 256 + kk * 16 + l];
            s  = fmaf(W1[d * DIM + h * 16 + kk], w2, s);
            sb = fmaf(bs[h * 16 + kk], w2, sb);
        }
        v = s * scale; b = sb * scale;
    }
    Wt[(size_t)c * DIM + d] = __float2bfloat16(v);
    if (d == 0) bias[c] = b;
}

// ---------------- proj: bf16 MFMA GEMM [N,128]@[128,640] ---------------------
// Persistent grid-stride kernel, 8 waves (512 thr), W register-resident.
// km layout is CHANNEL-PAIR interleaved: row r (512B) = 64 groups of 8B:
// group p = [katt ch 2p, 2p+1, mmsg ch 2p, 2p+1]. agg lane p loads one 8B
// group and does useful dot AND accumulate work (no wasted half-wave).
// katt/mmsg section pairs are computed together so the combined group is a
// single 16B store per lane.
__global__ __launch_bounds__(512) void proj_mfma(
    const float* __restrict__ x,             // [N][128] fp32
    const __hip_bfloat16* __restrict__ Wt,   // [768][128]
    const float* __restrict__ bias,          // [768]
    __hip_bfloat16* __restrict__ km,         // [2N][256] ch-pair interleaved
    __hip_bfloat16* __restrict__ qb)         // [N][128]
{
    __shared__ __align__(16) short xs[2][32 * DIM];   // 2 x 8 KB
    const int tid = threadIdx.x;
    const int wave = tid >> 6, lane = tid & 63;
    const int quad = lane >> 4, mcol = lane & 15;
    const int nt = N_NODES / 32;                      // 3125

    // ---- hoist W fragments + bias into registers (once) -------------------
    short8v wf[5][4];
    float4v bv[5];
    #pragma unroll
    for (int s = 0; s < 5; ++s) {
        const int c0 = s * 128 + wave * 16;
        const short* wp = (const short*)Wt + (size_t)(c0 + mcol) * DIM + quad * 8;
        #pragma unroll
        for (int kb = 0; kb < 4; ++kb)
            wf[s][kb] = *(const short8v*)(wp + kb * 32);
        bv[s] = *(const float4v*)(bias + c0 + quad * 4);
    }

    // ---- staging geometry: thread -> (row 0..31, 16B chunk 0..15) ----------
    const int srow = tid >> 4, sc8 = tid & 15;
    const int swz = ((sc8 ^ (srow & 7)) * 8);         // XOR-swizzled chunk

    int t = blockIdx.x;
    if (t >= nt) return;

    // prologue: stage tile t into buf0, prefetch tile t+G into regs
    float4v f0 = *(const float4v*)(x + (size_t)(t * 32 + srow) * DIM + sc8 * 8);
    float4v f1 = *(const float4v*)(x + (size_t)(t * 32 + srow) * DIM + sc8 * 8 + 4);
    {
        short8v sv;
        #pragma unroll
        for (int j = 0; j < 4; ++j) { sv[j] = bf16bits(f0[j]); sv[j + 4] = bf16bits(f1[j]); }
        *(short8v*)(xs[0] + srow * DIM + swz) = sv;
    }
    {
        int nn = t + PROJ_GRID;
        if (nn < nt) {
            f0 = *(const float4v*)(x + (size_t)(nn * 32 + srow) * DIM + sc8 * 8);
            f1 = *(const float4v*)(x + (size_t)(nn * 32 + srow) * DIM + sc8 * 8 + 4);
        }
    }

    int cur = 0;
    for (; t < nt; t += PROJ_GRID) {
        __syncthreads();   // buf[cur] fully staged; prev iter's reads complete

        // B fragments (x^T) for 32 rows: node = mcol (+16), k = quad*8 + j
        short8v b0[4], b1[4];
        #pragma unroll
        for (int kb = 0; kb < 4; ++kb) {
            const int ch = ((quad + kb * 4) ^ (mcol & 7)) * 8;
            b0[kb] = *(const short8v*)(xs[cur] + mcol * DIM + ch);
            b1[kb] = *(const short8v*)(xs[cur] + (mcol + 16) * DIM + ch);
        }

        const int r0 = t * 32;
        const int colb = wave * 32 + quad * 8;   // short offset within km row

        // ---- edge-set pairs: katt (sec e) + mmsg (sec 2+e) together -------
        #pragma unroll
        for (int e = 0; e < 2; ++e) {
            float4v aK0 = {0.f,0.f,0.f,0.f}, aK1 = {0.f,0.f,0.f,0.f};
            float4v aM0 = {0.f,0.f,0.f,0.f}, aM1 = {0.f,0.f,0.f,0.f};
            #pragma unroll
            for (int kb = 0; kb < 4; ++kb) {
                aK0 = __builtin_amdgcn_mfma_f32_16x16x32_bf16(wf[e][kb],     b0[kb], aK0, 0, 0, 0);
                aK1 = __builtin_amdgcn_mfma_f32_16x16x32_bf16(wf[e][kb],     b1[kb], aK1, 0, 0, 0);
                aM0 = __builtin_amdgcn_mfma_f32_16x16x32_bf16(wf[2 + e][kb], b0[kb], aM0, 0, 0, 0);
                aM1 = __builtin_amdgcn_mfma_f32_16x16x32_bf16(wf[2 + e][kb], b1[kb], aM1, 0, 0, 0);
            }
            short8v o0, o1;
            #pragma unroll
            for (int g = 0; g < 4; ++g) {
                const int pos = (g & 2) * 2 + (g & 1);   // 0,1,4,5
                o0[pos]     = bf16bits(aK0[g] + bv[e][g]);
                o0[pos + 2] = bf16bits(aM0[g] + bv[2 + e][g]);
                o1[pos]     = bf16bits(aK1[g] + bv[e][g]);
                o1[pos + 2] = bf16bits(aM1[g] + bv[2 + e][g]);
            }
            short* dp = (short*)km
                      + ((size_t)(r0 + mcol) + (size_t)e * N_NODES) * 256 + colb;
            *(short8v*)dp              = o0;
            *(short8v*)(dp + 16 * 256) = o1;
        }

        // ---- q section --------------------------------------------------
        {
            float4v a0v = {0.f,0.f,0.f,0.f}, a1v = {0.f,0.f,0.f,0.f};
            #pragma unroll
            for (int kb = 0; kb < 4; ++kb) {
                a0v = __builtin_amdgcn_mfma_f32_16x16x32_bf16(wf[4][kb], b0[kb], a0v, 0, 0, 0);
                a1v = __builtin_amdgcn_mfma_f32_16x16x32_bf16(wf[4][kb], b1[kb], a1v, 0, 0, 0);
            }
            short4v o0, o1;
            #pragma unroll
            for (int g = 0; g < 4; ++g) {
                o0[g] = bf16bits(a0v[g] + bv[4][g]);
                o1[g] = bf16bits(a1v[g] + bv[4][g]);
            }
            short* dp = (short*)qb + (size_t)(r0 + mcol) * DIM + wave * 16 + quad * 4;
            *(short4v*)dp              = o0;
            *(short4v*)(dp + 16 * DIM) = o1;
        }

        // stage tile t+G (already in f0/f1) into buf[cur^1]; prefetch t+2G
        int nn = t + PROJ_GRID;
        if (nn < nt) {
            short8v sv;
            #pragma unroll
            for (int j = 0; j < 4; ++j) { sv[j] = bf16bits(f0[j]); sv[j + 4] = bf16bits(f1[j]); }
            *(short8v*)(xs[cur ^ 1] + srow * DIM + swz) = sv;
            int n2 = nn + PROJ_GRID;
            if (n2 < nt) {
                f0 = *(const float4v*)(x + (size_t)(n2 * 32 + srow) * DIM + sc8 * 8);
                f1 = *(const float4v*)(x + (size_t)(n2 * 32 + srow) * DIM + sc8 * 8 + 4);
            }
        }
        cur ^= 1;
    }
}

// ---------------- CSR build ----------------
__global__ __launch_bounds__(256) void hist_kernel(
    const int* __restrict__ dst0, const int* __restrict__ dst1,
    int* __restrict__ counts)
{
    int e = blockIdx.x * 256 + threadIdx.x;
    if (e < E_EDGES) atomicAdd(&counts[dst0[e]], 1);
    int e1 = e - E_EDGES;
    if (e1 >= 0 && e1 < E_EDGES) atomicAdd(&counts[dst1[e1]], 1);
}

__global__ __launch_bounds__(SCAN_B) void scanA_kernel(
    const int* __restrict__ counts, int* __restrict__ row_ptr,
    int* __restrict__ bsum)
{
    __shared__ int buf[2][SCAN_B];
    int i = blockIdx.x * SCAN_B + threadIdx.x;
    int v = (i < N_NODES) ? counts[i] : 0;
    int cur = 0;
    buf[0][threadIdx.x] = v;
    __syncthreads();
    #pragma unroll
    for (int off = 1; off < SCAN_B; off <<= 1) {
        int t = buf[cur][threadIdx.x];
        int add = (threadIdx.x >= off) ? buf[cur][threadIdx.x - off] : 0;
        buf[cur ^ 1][threadIdx.x] = t + add;
        cur ^= 1;
        __syncthreads();
    }
    int inc = buf[cur][threadIdx.x];
    if (i < N_NODES) row_ptr[i] = inc - v;
    if (threadIdx.x == SCAN_B - 1) bsum[blockIdx.x] = inc;
}

// parallel exclusive scan of the (<=128) block sums, single block
__global__ __launch_bounds__(128) void scanB_kernel(int* __restrict__ bsum, int nblocks)
{
    __shared__ int buf[2][128];
    int t = threadIdx.x;
    int v = (t < nblocks) ? bsum[t] : 0;
    buf[0][t] = v;
    __syncthreads();
    int cur = 0;
    #pragma unroll
    for (int off = 1; off < 128; off <<= 1) {
        int a = buf[cur][t];
        if (t >= off) a += buf[cur][t - off];
        buf[cur ^ 1][t] = a;
        cur ^= 1;
        __syncthreads();
    }
    if (t < nblocks) bsum[t] = buf[cur][t] - v;   // exclusive
}

__global__ __launch_bounds__(SCAN_B) void scanC_kernel(
    int* __restrict__ row_ptr, int* __restrict__ cursor,
    const int* __restrict__ bsum)
{
    int i = blockIdx.x * SCAN_B + threadIdx.x;
    if (i < N_NODES) {
        int r = row_ptr[i] + bsum[blockIdx.x];
        row_ptr[i] = r;
        cursor[i] = r;
    }
}

__global__ __launch_bounds__(256) void scatter_kernel(
    const int* __restrict__ src0, const int* __restrict__ dst0,
    const int* __restrict__ src1, const int* __restrict__ dst1,
    int* __restrict__ cursor, unsigned int* __restrict__ eidx)
{
    int e = blockIdx.x * 256 + threadIdx.x;
    if (e < E_EDGES) {
        int d = dst0[e];
        int pos = atomicAdd(&cursor[d], 1);
        eidx[pos] = (unsigned int)src0[e];
    }
    int e1 = e - E_EDGES;
    if (e1 >= 0 && e1 < E_EDGES) {
        int d = dst1[e1];
        int pos = atomicAdd(&cursor[d], 1);
        eidx[pos] = (unsigned int)(src1[e1] + N_NODES);
    }
}

// ---------------- aggregation: one wave per node, no atomics -----------------
// km row = 64 x 8B groups [ka ch 2l,2l+1 | mg ch 2l,2l+1]. Lane l: ONE 8B load
// -> 2 dot FMAs (katt) + 2 acc FMAs (mmsg); zero wasted lanes. Head = 8 lanes
// -> 3-shuffle reduce; every lane owns its head's exp weight. 32-bit saddr
// addressing (km = 102 MB < 2^31).
__global__ __launch_bounds__(256) void agg_kernel(
    const char* __restrict__ km,        // [2N][512B]
    const unsigned* __restrict__ qv,    // [N][64] uint ch-pairs
    const int* __restrict__ row_ptr, const int* __restrict__ counts,
    const unsigned int* __restrict__ eidx,
    unsigned int* __restrict__ pooled)  // [N][64] uint (2 bf16 each)
{
    const int wave = threadIdx.x >> 6, lane = threadIdx.x & 63;
    const int n = blockIdx.x * 4 + wave;
    if (n >= N_NODES) return;
    const int start = row_ptr[n], cnt = counts[n];
    const unsigned lane8 = (unsigned)lane << 3;

    unsigned qu = qv[(size_t)n * 64 + lane];
    float q0, q1; bf2x2(qu, q0, q1);

    float a0 = 0.f, a1 = 0.f, den = 0.f;

#define EDGE_ACC(u)                                                          \
    {                                                                        \
        float k0, k1, m0, m1;                                                \
        bf2x2((u).x, k0, k1); bf2x2((u).y, m0, m1);                          \
        float p = fmaf(k1, q1, k0 * q0);                                     \
        p += __shfl_xor(p, 1, 64);                                           \
        p += __shfl_xor(p, 2, 64);                                           \
        p += __shfl_xor(p, 4, 64);                                           \
        float e = __expf(p);                                                 \
        den += e;                                                            \
        a0 = fmaf(e, m0, a0); a1 = fmaf(e, m1, a1);                          \
    }

    int i = 0;
    for (; i + 4 <= cnt; i += 4) {
        unsigned r0i = eidx[start + i];
        unsigned r1i = eidx[start + i + 1];
        unsigned r2i = eidx[start + i + 2];
        unsigned r3i = eidx[start + i + 3];
        uint2 u0 = *(const uint2*)(km + ((r0i << 9) | lane8));
        uint2 u1 = *(const uint2*)(km + ((r1i << 9) | lane8));
        uint2 u2 = *(const uint2*)(km + ((r2i << 9) | lane8));
        uint2 u3 = *(const uint2*)(km + ((r3i << 9) | lane8));
        EDGE_ACC(u0); EDGE_ACC(u1); EDGE_ACC(u2); EDGE_ACC(u3);
    }
    for (; i < cnt; ++i) {
        unsigned r0i = eidx[start + i];
        uint2 u0 = *(const uint2*)(km + ((r0i << 9) | lane8));
        EDGE_ACC(u0);
    }
#undef EDGE_ACC

    float v0 = 0.f, v1 = 0.f;
    if (den > 0.f) {
        float inv = 1.f / den;
        v0 = a0 * inv; v1 = a1 * inv;
    }
    v0 = 0.5f * v0 * (1.f + erff(v0 * 0.70710678118654752f));
    v1 = 0.5f * v1 * (1.f + erff(v1 * 0.70710678118654752f));

    unsigned packed = ((unsigned)(unsigned short)bf16bits(v0))
                    | ((unsigned)(unsigned short)bf16bits(v1) << 16);
    pooled[(size_t)n * 64 + lane] = packed;
}

// ---------------- final: MFMA GEMM(Wa) -> skip -> LayerNorm ------------------
__global__ __launch_bounds__(256) void final_mfma(
    const __hip_bfloat16* __restrict__ pooled,  // [N][128] bf16, gelu applied
    const __hip_bfloat16* __restrict__ Wt,      // [768][128]; rows 640.. = Wa^T
    const float* __restrict__ bias,             // [768]; 640.. = ba
    const float* __restrict__ x,
    const float* __restrict__ skip, const float* __restrict__ gamma,
    const float* __restrict__ beta, float* __restrict__ out)
{
    __shared__ float hs[32][DIM];
    const int wave = threadIdx.x >> 6, lane = threadIdx.x & 63;
    const int quad = lane >> 4, mcol = lane & 15;
    const int r0 = blockIdx.x * 32;

    short8v a0[4], a1[4];
    const short* pp0 = (const short*)pooled + (size_t)(r0 + mcol) * DIM + quad * 8;
    const short* pp1 = pp0 + 16 * DIM;
    #pragma unroll
    for (int kb = 0; kb < 4; ++kb) {
        a0[kb] = *(const short8v*)(pp0 + kb * 32);
        a1[kb] = *(const short8v*)(pp1 + kb * 32);
    }
    const float alpha = 1.f / (1.f + expf(-skip[0]));

    #pragma unroll
    for (int t = 0; t < 2; ++t) {
        const int c0 = wave * 32 + t * 16;
        const short* wp = (const short*)Wt + (size_t)(640 + c0 + mcol) * DIM + quad * 8;
        float4v acc0 = {0.f, 0.f, 0.f, 0.f};
        float4v acc1 = {0.f, 0.f, 0.f, 0.f};
        #pragma unroll
        for (int kb = 0; kb < 4; ++kb) {
            short8v bfr = *(const short8v*)(wp + kb * 32);
            acc0 = __builtin_amdgcn_mfma_f32_16x16x32_bf16(a0[kb], bfr, acc0, 0, 0, 0);
            acc1 = __builtin_amdgcn_mfma_f32_16x16x32_bf16(a1[kb], bfr, acc1, 0, 0, 0);
        }
        const float bcol = bias[640 + c0 + mcol];
        const int cc = c0 + mcol;
        const int rq = quad * 4;
        #pragma unroll
        for (int g = 0; g < 4; ++g) {
            int rA = rq + g, rB = rq + 16 + g;
            hs[rA][cc] = alpha * (acc0[g] + bcol)
                       + (1.f - alpha) * x[(size_t)(r0 + rA) * DIM + cc];
            hs[rB][cc] = alpha * (acc1[g] + bcol)
                       + (1.f - alpha) * x[(size_t)(r0 + rB) * DIM + cc];
        }
    }
    __syncthreads();

    float gam0 = gamma[lane], gam1 = gamma[lane + 64];
    float bet0 = beta[lane],  bet1 = beta[lane + 64];
    for (int r = wave; r < 32; r += 4) {
        int row = r0 + r;
        float v0 = hs[r][lane], v1 = hs[r][lane + 64];
        float s = v0 + v1, s2 = v0 * v0 + v1 * v1;
        #pragma unroll
        for (int off = 1; off < 64; off <<= 1) {
            s  += __shfl_xor(s,  off, 64);
            s2 += __shfl_xor(s2, off, 64);
        }
        float mu = s * (1.f / 128.f);
        float var = s2 * (1.f / 128.f) - mu * mu;
        float rstd = rsqrtf(var + LN_EPS);
        out[(size_t)row * DIM + lane]      = (v0 - mu) * rstd * gam0 + bet0;
        out[(size_t)row * DIM + lane + 64] = (v1 - mu) * rstd * gam1 + bet1;
    }
}

extern "C" void kernel_launch(void* const* d_in, const int* in_sizes, int n_in,
                              void* d_out, int out_size, void* d_ws, size_t ws_size,
                              hipStream_t stream) {
    const float* x     = (const float*)d_in[0];
    const int*   src0  = (const int*)d_in[1];
    const int*   dst0  = (const int*)d_in[2];
    const int*   src1  = (const int*)d_in[3];
    const int*   dst1  = (const int*)d_in[4];
    const float* Wk    = (const float*)d_in[5];
    const float* bk    = (const float*)d_in[6];
    const float* Wm    = (const float*)d_in[7];
    const float* bm    = (const float*)d_in[8];
    const float* Wq    = (const float*)d_in[9];
    const float* bq    = (const float*)d_in[10];
    const float* Wa    = (const float*)d_in[11];
    const float* ba    = (const float*)d_in[12];
    const float* Watt0 = (const float*)d_in[13];
    const float* Wmsg0 = (const float*)d_in[14];
    const float* Watt1 = (const float*)d_in[15];
    const float* Wmsg1 = (const float*)d_in[16];
    const float* prior0= (const float*)d_in[17];
    const float* prior1= (const float*)d_in[18];
    const float* skip  = (const float*)d_in[19];
    const float* gamma = (const float*)d_in[20];
    const float* beta  = (const float*)d_in[21];
    float* out = (float*)d_out;

    const size_t nd = (size_t)N_NODES * DIM;
    // Workspace (~158 MB):
    //   Wt [768*128 bf16] | bias [768 f32] | km [2N*256 bf16 pair-interleaved]
    //   | qb [nd bf16] | pooled [nd bf16] | counts/row_ptr/cursor [N i32]
    //   | bsum [128 i32] | eidx [2E u32]
    char* wsb = (char*)d_ws;
    __hip_bfloat16* Wt    = (__hip_bfloat16*)wsb;  wsb += (size_t)768 * DIM * 2;
    float* bias           = (float*)wsb;           wsb += 768 * 4;
    __hip_bfloat16* km    = (__hip_bfloat16*)wsb;  wsb += (size_t)2 * N_NODES * 256 * 2;
    __hip_bfloat16* qb    = (__hip_bfloat16*)wsb;  wsb += nd * 2;
    __hip_bfloat16* pooled= (__hip_bfloat16*)wsb;  wsb += nd * 2;
    int* counts  = (int*)wsb;                      wsb += (size_t)N_NODES * 4;
    int* row_ptr = (int*)wsb;                      wsb += (size_t)N_NODES * 4;
    int* cursor  = (int*)wsb;                      wsb += (size_t)N_NODES * 4;
    int* bsum    = (int*)wsb;                      wsb += 128 * 4;
    unsigned int* eidx = (unsigned int*)wsb;

    hipMemsetAsync(counts, 0, (size_t)N_NODES * 4, stream);

    const int scan_blocks = (N_NODES + SCAN_B - 1) / SCAN_B;   // 98
    const int edge_blocks = (2 * E_EDGES + 255) / 256;         // 3125

    // CSR chain (independent of projections)
    hist_kernel<<<dim3(edge_blocks), dim3(256), 0, stream>>>(dst0, dst1, counts);
    scanA_kernel<<<dim3(scan_blocks), dim3(SCAN_B), 0, stream>>>(counts, row_ptr, bsum);
    scanB_kernel<<<dim3(1), dim3(128), 0, stream>>>(bsum, scan_blocks);
    scanC_kernel<<<dim3(scan_blocks), dim3(SCAN_B), 0, stream>>>(row_ptr, cursor, bsum);
    scatter_kernel<<<dim3(edge_blocks), dim3(256), 0, stream>>>(
        src0, dst0, src1, dst1, cursor, eidx);

    // Projections
    fuse_weights<<<dim3(768), dim3(128), 0, stream>>>(
        Wk, bk, Wm, bm, Wq, bq, Wa, ba,
        Watt0, Wmsg0, Watt1, Wmsg1, prior0, prior1, Wt, bias);
    proj_mfma<<<dim3(PROJ_GRID), dim3(512), 0, stream>>>(
        x, Wt, bias, km, qb);

    agg_kernel<<<dim3((N_NODES + 3) / 4), dim3(256), 0, stream>>>(
        (const char*)km, (const unsigned*)qb, row_ptr, counts, eidx,
        (unsigned int*)pooled);

    final_mfma<<<dim3(N_NODES / 32), dim3(256), 0, stream>>>(
        pooled, Wt, bias, x, skip, gamma, beta, out);
}